// Round 5
// baseline (698.523 us; speedup 1.0000x reference)
//
#include <hip/hip_runtime.h>
#include <cmath>

#define NN 50000
#define EE 800000
#define ETOT (EE + NN)
#define NSCAN ((NN + 1023) / 1024)

typedef __bf16 v8bf __attribute__((ext_vector_type(8)));
typedef float f32x4 __attribute__((ext_vector_type(4)));

__device__ __forceinline__ float lrelu(float x){ return x > 0.0f ? x : 0.2f * x; }
__device__ __forceinline__ unsigned short f2bf_rne(float x){
  unsigned int u = __float_as_uint(x);
  u += 0x7fffu + ((u >> 16) & 1u);
  return (unsigned short)(u >> 16);
}
__device__ __forceinline__ float bf2f(unsigned short b){
  return __uint_as_float(((unsigned int)b) << 16);
}
// pack (src u16 | f16(w) << 16)
__device__ __forceinline__ unsigned pack_sw(int src, float w){
  union { _Float16 f; unsigned short u; } cv;
  cv.f = (_Float16)w;
  return (unsigned)(src & 0xffff) | ((unsigned)cv.u << 16);
}
__device__ __forceinline__ float unpack_w(unsigned m){
  union { unsigned short u; _Float16 f; } cv;
  cv.u = (unsigned short)(m >> 16);
  return (float)cv.f;
}

// ---------------- CSR build ----------------
__global__ void k_hist(const int* __restrict__ dst, int* __restrict__ cnt){
  int i = blockIdx.x * 256 + threadIdx.x;
  if (i >= ETOT) return;
  int d = (i < EE) ? dst[i] : (i - EE);
  atomicAdd(&cnt[d], 1);
}

__global__ void k_scan1(const int* __restrict__ cnt, int* __restrict__ part){
  __shared__ int sm[256];
  int b = blockIdx.x, t = threadIdx.x;
  int base = b * 1024 + t * 4;
  int s = 0;
  #pragma unroll
  for (int j = 0; j < 4; j++) if (base + j < NN) s += cnt[base + j];
  sm[t] = s; __syncthreads();
  for (int off = 128; off; off >>= 1){
    if (t < off) sm[t] += sm[t + off];
    __syncthreads();
  }
  if (t == 0) part[b] = sm[0];
}

__global__ void k_scan2(const int* __restrict__ part, int* __restrict__ part2){
  if (threadIdx.x == 0 && blockIdx.x == 0){
    int run = 0;
    for (int i = 0; i < NSCAN; i++){ part2[i] = run; run += part[i]; }
  }
}

__global__ void k_scan3(const int* __restrict__ cnt, const int* __restrict__ part2,
                        int* __restrict__ rowptr){
  __shared__ int sm[256];
  int b = blockIdx.x, t = threadIdx.x;
  int base = b * 1024 + t * 4;
  int v[4]; int s = 0;
  #pragma unroll
  for (int j = 0; j < 4; j++){ v[j] = (base + j < NN) ? cnt[base + j] : 0; s += v[j]; }
  sm[t] = s; __syncthreads();
  for (int off = 1; off < 256; off <<= 1){
    int x = (t >= off) ? sm[t - off] : 0;
    __syncthreads();
    sm[t] += x;
    __syncthreads();
  }
  int run = part2[b] + sm[t] - s;
  #pragma unroll
  for (int j = 0; j < 4; j++){
    if (base + j < NN){ rowptr[base + j] = run; run += v[j]; }
  }
  if (b == 0 && t == 0) rowptr[NN] = ETOT;
}

__global__ void k_scatter(const int* __restrict__ src, const int* __restrict__ dst,
                          const int* __restrict__ rowptr, int* __restrict__ fill,
                          int* __restrict__ csr){
  int i = blockIdx.x * 256 + threadIdx.x;
  if (i >= ETOT) return;
  int s, d;
  if (i < EE){ s = src[i]; d = dst[i]; } else { s = d = i - EE; }
  int pos = rowptr[d] + atomicAdd(&fill[d], 1);
  csr[pos] = s;
}

// ---------------- weight conversion: fp32 [.,K,N] -> bf16 hi/lo [.,K/8,N,8] ----
__global__ void k_convB(const float* __restrict__ B, unsigned short* __restrict__ bh,
                        unsigned short* __restrict__ bl, int K, int N, int total){
  int i = blockIdx.x * 256 + threadIdx.x;
  if (i >= total) return;
  int per = K * N;
  int h = i / per, rem = i - h * per;
  int k = rem / N, n = rem - k * N;
  float x = B[i];
  unsigned short hb = f2bf_rne(x);
  unsigned short lb = f2bf_rne(x - bf2f(hb));
  size_t o = (size_t)h * per + ((size_t)(k >> 3) * N + n) * 8 + (k & 7);
  bh[o] = hb; bl[o] = lb;
}

// ---------------- split-bf16 MFMA GEMM, slice-major bf16 output ----------------
// out[(col>>5)*NN*32 + row*32 + (col&31)]
template<int BN>
__global__ __launch_bounds__(256) void gemm_split(const float* __restrict__ A,
                                                  const unsigned short* __restrict__ Bh,
                                                  const unsigned short* __restrict__ Bl,
                                                  unsigned short* __restrict__ out,
                                                  int M, int K){
  const int t = threadIdx.x;
  const int wv = t >> 6, lane = t & 63;
  const int m0 = blockIdx.x * 128;
  const int h = blockIdx.y;
  A  += (size_t)h * M * K;
  Bh += (size_t)h * (K >> 3) * BN * 8;
  Bl += (size_t)h * (K >> 3) * BN * 8;
  const int colOff = h * BN;

  __shared__ v8bf sAh[4][128];
  __shared__ v8bf sAl[4][128];
  __shared__ v8bf sBh[4][BN];
  __shared__ v8bf sBl[4][BN];

  f32x4 acc[2][BN / 16];
  #pragma unroll
  for (int i = 0; i < 2; i++)
    #pragma unroll
    for (int j = 0; j < BN / 16; j++){
      f32x4 z = {0.f, 0.f, 0.f, 0.f};
      acc[i][j] = z;
    }

  const int mRow = t & 127;
  const int kh = (t >> 7) * 16;
  const bool valid = (m0 + mRow) < M;
  const int q = lane >> 4, lm = lane & 15;

  for (int k0 = 0; k0 < K; k0 += 32){
    const float* ap = A + (size_t)(m0 + mRow) * K + k0 + kh;
    float4 v0, v1, v2, v3;
    if (valid){
      v0 = *(const float4*)(ap);
      v1 = *(const float4*)(ap + 4);
      v2 = *(const float4*)(ap + 8);
      v3 = *(const float4*)(ap + 12);
    } else {
      v0 = v1 = v2 = v3 = make_float4(0.f, 0.f, 0.f, 0.f);
    }
    #pragma unroll
    for (int g = 0; g < 2; g++){
      float xv[8];
      if (g == 0){ xv[0]=v0.x; xv[1]=v0.y; xv[2]=v0.z; xv[3]=v0.w; xv[4]=v1.x; xv[5]=v1.y; xv[6]=v1.z; xv[7]=v1.w; }
      else       { xv[0]=v2.x; xv[1]=v2.y; xv[2]=v2.z; xv[3]=v2.w; xv[4]=v3.x; xv[5]=v3.y; xv[6]=v3.z; xv[7]=v3.w; }
      union { v8bf v; unsigned short u[8]; } H, L;
      #pragma unroll
      for (int i = 0; i < 8; i++){
        unsigned short hb = f2bf_rne(xv[i]);
        H.u[i] = hb;
        L.u[i] = f2bf_rne(xv[i] - bf2f(hb));
      }
      int k8 = (kh >> 3) + g;
      sAh[k8][mRow] = H.v;
      sAl[k8][mRow] = L.v;
    }
    {
      const v8bf* gh = (const v8bf*)Bh + (size_t)(k0 >> 3) * BN;
      const v8bf* gl = (const v8bf*)Bl + (size_t)(k0 >> 3) * BN;
      v8bf* dh = &sBh[0][0];
      v8bf* dl = &sBl[0][0];
      #pragma unroll
      for (int i = t; i < 4 * BN; i += 256){ dh[i] = gh[i]; dl[i] = gl[i]; }
    }
    __syncthreads();
    v8bf ah[2], al[2];
    #pragma unroll
    for (int rt = 0; rt < 2; rt++){
      int m = wv * 32 + rt * 16 + lm;
      ah[rt] = sAh[q][m];
      al[rt] = sAl[q][m];
    }
    #pragma unroll
    for (int ct = 0; ct < BN / 16; ct++){
      v8bf bh = sBh[q][ct * 16 + lm];
      v8bf bl = sBl[q][ct * 16 + lm];
      #pragma unroll
      for (int rt = 0; rt < 2; rt++){
        acc[rt][ct] = __builtin_amdgcn_mfma_f32_16x16x32_bf16(ah[rt], bh, acc[rt][ct], 0, 0, 0);
        acc[rt][ct] = __builtin_amdgcn_mfma_f32_16x16x32_bf16(ah[rt], bl, acc[rt][ct], 0, 0, 0);
        acc[rt][ct] = __builtin_amdgcn_mfma_f32_16x16x32_bf16(al[rt], bh, acc[rt][ct], 0, 0, 0);
      }
    }
    __syncthreads();
  }

  #pragma unroll
  for (int rt = 0; rt < 2; rt++){
    #pragma unroll
    for (int reg = 0; reg < 4; reg++){
      int r = m0 + wv * 32 + rt * 16 + q * 4 + reg;
      if (r < M){
        #pragma unroll
        for (int ct = 0; ct < BN / 16; ct++){
          int col = colOff + ct * 16 + lm;
          out[((size_t)(col >> 5) * NN + r) * 32 + (col & 31)] = f2bf_rne(acc[rt][ct][reg]);
        }
      }
    }
  }
}

// ---------------- layer-1 attention logits, all 4 heads (sliced xs) ----------
__global__ __launch_bounds__(256) void k_rowdot_all(const unsigned short* __restrict__ xs_sl,
                                                    const float* __restrict__ att_src,
                                                    const float* __restrict__ att_dst,
                                                    float* __restrict__ ssrc,
                                                    float* __restrict__ sdst){
  int n = (blockIdx.x * 256 + threadIdx.x) >> 6;
  int lane = threadIdx.x & 63;
  if (n >= NN) return;
  int h = lane >> 4, c8 = lane & 15;
  uint4 u = ((const uint4*)xs_sl)[((size_t)(lane >> 2) * NN + n) * 4 + (lane & 3)];
  const float* as = att_src + lane * 8;
  const float* ad = att_dst + lane * 8;
  float4 a0 = *(const float4*)as, a1 = *(const float4*)(as + 4);
  float4 b0 = *(const float4*)ad, b1 = *(const float4*)(ad + 4);
  float f[8];
  f[0] = __uint_as_float(u.x << 16); f[1] = __uint_as_float(u.x & 0xffff0000u);
  f[2] = __uint_as_float(u.y << 16); f[3] = __uint_as_float(u.y & 0xffff0000u);
  f[4] = __uint_as_float(u.z << 16); f[5] = __uint_as_float(u.z & 0xffff0000u);
  f[6] = __uint_as_float(u.w << 16); f[7] = __uint_as_float(u.w & 0xffff0000u);
  float d0 = f[0]*a0.x + f[1]*a0.y + f[2]*a0.z + f[3]*a0.w
           + f[4]*a1.x + f[5]*a1.y + f[6]*a1.z + f[7]*a1.w;
  float d1 = f[0]*b0.x + f[1]*b0.y + f[2]*b0.z + f[3]*b0.w
           + f[4]*b1.x + f[5]*b1.y + f[6]*b1.z + f[7]*b1.w;
  #pragma unroll
  for (int off = 1; off < 16; off <<= 1){
    d0 += __shfl_xor(d0, off, 64);
    d1 += __shfl_xor(d1, off, 64);
  }
  if (c8 == 0){ ssrc[n * 4 + h] = d0; sdst[n * 4 + h] = d1; }
}

// ---------------- layer-1 meta: normalized softmax weights packed (src,w) ----
// No max-subtraction (logits small; exp safe in fp32). meta[h*ETOT+e].
__global__ __launch_bounds__(256) void k_meta4(const int* __restrict__ rowptr,
                                               const int* __restrict__ csr,
                                               const float* __restrict__ ssrc,
                                               const float* __restrict__ sdst,
                                               unsigned* __restrict__ meta){
  int n = (blockIdx.x * 256 + threadIdx.x) >> 6;
  int lane = threadIdx.x & 63;
  if (n >= NN) return;
  int start = rowptr[n], end = rowptr[n + 1];
  float4 sd = ((const float4*)sdst)[n];

  float s0 = 0.f, s1 = 0.f, s2 = 0.f, s3 = 0.f;
  for (int e = start + lane; e < end; e += 64){
    float4 sv = ((const float4*)ssrc)[csr[e]];
    s0 += __expf(lrelu(sv.x + sd.x));
    s1 += __expf(lrelu(sv.y + sd.y));
    s2 += __expf(lrelu(sv.z + sd.z));
    s3 += __expf(lrelu(sv.w + sd.w));
  }
  #pragma unroll
  for (int off = 32; off; off >>= 1){
    s0 += __shfl_xor(s0, off, 64);
    s1 += __shfl_xor(s1, off, 64);
    s2 += __shfl_xor(s2, off, 64);
    s3 += __shfl_xor(s3, off, 64);
  }
  float i0 = 1.f / s0, i1 = 1.f / s1, i2 = 1.f / s2, i3 = 1.f / s3;

  for (int e = start + lane; e < end; e += 64){
    int src = csr[e];
    float4 sv = ((const float4*)ssrc)[src];
    meta[e]            = pack_sw(src, __expf(lrelu(sv.x + sd.x)) * i0);
    meta[ETOT + e]     = pack_sw(src, __expf(lrelu(sv.y + sd.y)) * i1);
    meta[2 * ETOT + e] = pack_sw(src, __expf(lrelu(sv.z + sd.z)) * i2);
    meta[3 * ETOT + e] = pack_sw(src, __expf(lrelu(sv.w + sd.w)) * i3);
  }
}

// ---------------- layer-1 XCD-pinned sliced gather ----------------
// 16 slices x 32 feats (3.2MB, L2-resident). blockIdx%8 pins slice to XCD.
// Wave = 8 nodes (one per 8-lane group), no cross-lane reduction.
__global__ __launch_bounds__(256) void k_gs1(const int* __restrict__ rowptr,
                                             const unsigned* __restrict__ meta,
                                             const unsigned short* __restrict__ tab,
                                             const float* __restrict__ bias,
                                             float* __restrict__ x1){
  int b = blockIdx.x;
  int phase = b / 12504;              // 8 * 1563
  int r = b - phase * 12504;
  int xcd = r & 7, blk = r >> 3;      // blk 0..1562
  int slice = phase * 8 + xcd;
  int wv = threadIdx.x >> 6, lane = threadIdx.x & 63;
  int g = lane >> 3, l = lane & 7;
  int n = (blk * 4 + wv) * 8 + g;
  bool vn = n < NN;
  int nc = vn ? n : 0;
  int start = rowptr[nc];
  int end = vn ? rowptr[nc + 1] : start;

  const unsigned* mh = meta + (size_t)(slice >> 2) * ETOT;
  const unsigned short* tb = tab + (size_t)slice * NN * 32;
  f32x4 acc = {0.f, 0.f, 0.f, 0.f};

  for (int e = start; ; e++){
    bool act = e < end;
    if (!__any(act)) break;
    if (act){
      unsigned m = __builtin_nontemporal_load(mh + e);
      int src = m & 0xffff;
      float w = unpack_w(m);
      uint2 u = *(const uint2*)(tb + (size_t)src * 32 + l * 4);
      acc.x += w * __uint_as_float(u.x << 16);
      acc.y += w * __uint_as_float(u.x & 0xffff0000u);
      acc.z += w * __uint_as_float(u.y << 16);
      acc.w += w * __uint_as_float(u.y & 0xffff0000u);
    }
  }
  if (vn){
    const float* bp = bias + slice * 32 + l * 4;
    float4 bb = *(const float4*)bp;
    f32x4 o;
    o.x = lrelu(acc.x + bb.x);
    o.y = lrelu(acc.y + bb.y);
    o.z = lrelu(acc.z + bb.z);
    o.w = lrelu(acc.w + bb.w);
    __builtin_nontemporal_store(o, (f32x4*)(x1 + (size_t)n * 512 + slice * 32 + l * 4));
  }
}

// ---------------- layer-2 logits (sliced xs2) ----------------
__global__ __launch_bounds__(256) void k_rowdot2(const unsigned short* __restrict__ xs2_sl,
                                                 const float* __restrict__ as,
                                                 const float* __restrict__ ad,
                                                 float* __restrict__ ssrc,
                                                 float* __restrict__ sdst){
  int idx = blockIdx.x * 256 + threadIdx.x;
  int n = idx >> 5, sub = idx & 31;
  if (n >= NN) return;
  unsigned int u = ((const unsigned int*)xs2_sl)[((size_t)(sub >> 4) * NN + n) * 16 + (sub & 15)];
  float f0 = __uint_as_float(u << 16);
  float f1 = __uint_as_float(u & 0xffff0000u);
  float d0 = f0 * as[sub * 2] + f1 * as[sub * 2 + 1];
  float d1 = f0 * ad[sub * 2] + f1 * ad[sub * 2 + 1];
  #pragma unroll
  for (int off = 1; off < 32; off <<= 1){
    d0 += __shfl_xor(d0, off, 64);
    d1 += __shfl_xor(d1, off, 64);
  }
  if (sub == 0){ ssrc[n] = d0; sdst[n] = d1; }
}

// ---------------- layer-2 meta ----------------
__global__ __launch_bounds__(256) void k_meta1(const int* __restrict__ rowptr,
                                               const int* __restrict__ csr,
                                               const float* __restrict__ ssrc,
                                               const float* __restrict__ sdst,
                                               unsigned* __restrict__ meta){
  int n = (blockIdx.x * 256 + threadIdx.x) >> 6;
  int lane = threadIdx.x & 63;
  if (n >= NN) return;
  int start = rowptr[n], end = rowptr[n + 1];
  float sdn = sdst[n];

  float sloc = 0.f;
  for (int e = start + lane; e < end; e += 64)
    sloc += __expf(lrelu(ssrc[csr[e]] + sdn));
  #pragma unroll
  for (int off = 32; off; off >>= 1) sloc += __shfl_xor(sloc, off, 64);
  float inv = 1.f / sloc;

  for (int e = start + lane; e < end; e += 64){
    int src = csr[e];
    meta[e] = pack_sw(src, __expf(lrelu(ssrc[src] + sdn)) * inv);
  }
}

// ---------------- layer-2 XCD-pinned sliced gather (final output) ----------
// 2 slices x 32 feats; XCDs 0-3 -> slice 0, XCDs 4-7 -> slice 1.
__global__ __launch_bounds__(256) void k_gs2(const int* __restrict__ rowptr,
                                             const unsigned* __restrict__ meta,
                                             const unsigned short* __restrict__ tab,
                                             const float* __restrict__ bias,
                                             float* __restrict__ outp){
  int b = blockIdx.x;
  int xcd = b & 7, blk = b >> 3;       // blk 0..390
  int slice = xcd >> 2, sub = xcd & 3;
  int i = sub * 391 + blk;             // 0..1563
  int wv = threadIdx.x >> 6, lane = threadIdx.x & 63;
  int g = lane >> 3, l = lane & 7;
  int n = (i * 4 + wv) * 8 + g;
  bool vn = n < NN;
  int nc = vn ? n : 0;
  int start = rowptr[nc];
  int end = vn ? rowptr[nc + 1] : start;

  const unsigned short* tb = tab + (size_t)slice * NN * 32;
  f32x4 acc = {0.f, 0.f, 0.f, 0.f};

  for (int e = start; ; e++){
    bool act = e < end;
    if (!__any(act)) break;
    if (act){
      unsigned m = __builtin_nontemporal_load(meta + e);
      int src = m & 0xffff;
      float w = unpack_w(m);
      uint2 u = *(const uint2*)(tb + (size_t)src * 32 + l * 4);
      acc.x += w * __uint_as_float(u.x << 16);
      acc.y += w * __uint_as_float(u.x & 0xffff0000u);
      acc.z += w * __uint_as_float(u.y << 16);
      acc.w += w * __uint_as_float(u.y & 0xffff0000u);
    }
  }
  if (vn){
    const float* bp = bias + slice * 32 + l * 4;
    float4 bb = *(const float4*)bp;
    f32x4 o;
    o.x = tanhf(lrelu(acc.x + bb.x));
    o.y = tanhf(lrelu(acc.y + bb.y));
    o.z = tanhf(lrelu(acc.z + bb.z));
    o.w = tanhf(lrelu(acc.w + bb.w));
    __builtin_nontemporal_store(o, (f32x4*)(outp + (size_t)n * 64 + slice * 32 + l * 4));
  }
}

extern "C" void kernel_launch(void* const* d_in, const int* in_sizes, int n_in,
                              void* d_out, int out_size, void* d_ws, size_t ws_size,
                              hipStream_t stream){
  const float* type_emb  = (const float*)d_in[0];
  const int*   edge      = (const int*)d_in[1];
  const float* W         = (const float*)d_in[2];
  const float* att_src   = (const float*)d_in[3];
  const float* att_dst   = (const float*)d_in[4];
  const float* bias      = (const float*)d_in[5];
  const float* W_out     = (const float*)d_in[6];
  const float* att_src_o = (const float*)d_in[7];
  const float* att_dst_o = (const float*)d_in[8];
  const float* bias_o    = (const float*)d_in[9];
  float* out = (float*)d_out;
  (void)in_sizes; (void)n_in; (void)out_size; (void)ws_size;

  char* ws = (char*)d_ws;
  size_t off = 0;
  auto alloc = [&](size_t bytes) -> void* {
    void* p = ws + off;
    off = (off + bytes + 255) & ~(size_t)255;
    return p;
  };
  unsigned short* xs_sl1 = (unsigned short*)alloc((size_t)NN * 512 * 2); // [16][N][32] bf16
  float*          x1     = (float*)alloc((size_t)NN * 512 * 4);          // [N][512] fp32
  unsigned short* xs2_sl = (unsigned short*)alloc((size_t)NN * 64 * 2);  // [2][N][32] bf16
  unsigned* meta4 = (unsigned*)alloc((size_t)4 * ETOT * 4);              // [4][E] (src,u16|w f16)
  unsigned* meta2 = (unsigned*)alloc((size_t)ETOT * 4);                  // [E]
  float* ssrc1 = (float*)alloc((size_t)NN * 4 * 4);
  float* sdst1 = (float*)alloc((size_t)NN * 4 * 4);
  float* ssrc2 = (float*)alloc((size_t)NN * 4);
  float* sdst2 = (float*)alloc((size_t)NN * 4);
  int* cnt    = (int*)alloc((size_t)NN * 4);
  int* rowptr = (int*)alloc((size_t)(NN + 1) * 4);
  int* fill   = (int*)alloc((size_t)NN * 4);
  int* csr    = (int*)alloc((size_t)ETOT * 4);
  int* p1     = (int*)alloc((size_t)NSCAN * 4 + 256);
  int* p2     = (int*)alloc((size_t)NSCAN * 4 + 256);
  unsigned short* Bh1 = (unsigned short*)alloc((size_t)4 * 128 * 128 * 2);
  unsigned short* Bl1 = (unsigned short*)alloc((size_t)4 * 128 * 128 * 2);
  unsigned short* Bh2 = (unsigned short*)alloc((size_t)512 * 64 * 2);
  unsigned short* Bl2 = (unsigned short*)alloc((size_t)512 * 64 * 2);

  // ---- CSR build (dst-sorted) ----
  hipMemsetAsync(cnt, 0, (size_t)NN * 4, stream);
  hipMemsetAsync(fill, 0, (size_t)NN * 4, stream);
  k_hist<<<(ETOT + 255) / 256, 256, 0, stream>>>(edge + EE, cnt);
  k_scan1<<<NSCAN, 256, 0, stream>>>(cnt, p1);
  k_scan2<<<1, 64, 0, stream>>>(p1, p2);
  k_scan3<<<NSCAN, 256, 0, stream>>>(cnt, p2, rowptr);
  k_scatter<<<(ETOT + 255) / 256, 256, 0, stream>>>(edge, edge + EE, rowptr, fill, csr);

  // ---- weight conversion ----
  k_convB<<<(4 * 128 * 128 + 255) / 256, 256, 0, stream>>>(W, Bh1, Bl1, 128, 128, 4 * 128 * 128);
  k_convB<<<(512 * 64 + 255) / 256, 256, 0, stream>>>(W_out, Bh2, Bl2, 512, 64, 512 * 64);

  // ---- layer 1 ----
  gemm_split<128><<<dim3(391, 4), 256, 0, stream>>>(type_emb, Bh1, Bl1, xs_sl1, NN, 128);
  k_rowdot_all<<<12500, 256, 0, stream>>>(xs_sl1, att_src, att_dst, ssrc1, sdst1);
  k_meta4<<<12500, 256, 0, stream>>>(rowptr, csr, ssrc1, sdst1, meta4);
  k_gs1<<<25008, 256, 0, stream>>>(rowptr, meta4, xs_sl1, bias, x1);

  // ---- layer 2 ----
  gemm_split<64><<<dim3(391, 1), 256, 0, stream>>>(x1, Bh2, Bl2, xs2_sl, NN, 512);
  k_rowdot2<<<(NN * 32 + 255) / 256, 256, 0, stream>>>(xs2_sl, att_src_o, att_dst_o, ssrc2, sdst2);
  k_meta1<<<12500, 256, 0, stream>>>(rowptr, csr, ssrc2, sdst2, meta2);
  k_gs2<<<3128, 256, 0, stream>>>(rowptr, meta2, xs2_sl, bias_o, out);
}

// Round 7
// 683.094 us; speedup vs baseline: 1.0226x; 1.0226x over previous
//
#include <hip/hip_runtime.h>
#include <cmath>

#define NN 50000
#define EE 800000
#define ETOT (EE + NN)
#define NSCAN ((NN + 1023) / 1024)

typedef __bf16 v8bf __attribute__((ext_vector_type(8)));
typedef float f32x4 __attribute__((ext_vector_type(4)));
typedef float f32x2 __attribute__((ext_vector_type(2)));

__device__ __forceinline__ float lrelu(float x){ return x > 0.0f ? x : 0.2f * x; }
__device__ __forceinline__ unsigned bcast_u(unsigned v, int j){
  return (unsigned)__builtin_amdgcn_readlane((int)v, j);
}
__device__ __forceinline__ unsigned short f2bf_rne(float x){
  unsigned int u = __float_as_uint(x);
  u += 0x7fffu + ((u >> 16) & 1u);
  return (unsigned short)(u >> 16);
}
__device__ __forceinline__ float f16_lo(unsigned u){
  union { unsigned short s; _Float16 f; } c; c.s = (unsigned short)(u & 0xffffu); return (float)c.f;
}
__device__ __forceinline__ float f16_hi(unsigned u){
  union { unsigned short s; _Float16 f; } c; c.s = (unsigned short)(u >> 16); return (float)c.f;
}
__device__ __forceinline__ unsigned pack_f16x2(float a, float b){
  union { _Float16 f; unsigned short s; } ca, cb;
  ca.f = (_Float16)a; cb.f = (_Float16)b;
  return (unsigned)ca.s | ((unsigned)cb.s << 16);
}
// pack (src u16 | f16(w) << 16)
__device__ __forceinline__ unsigned pack_sw(int src, float w){
  union { _Float16 f; unsigned short u; } cv;
  cv.f = (_Float16)w;
  return (unsigned)(src & 0xffff) | ((unsigned)cv.u << 16);
}

// ---------------- CSR build ----------------
__global__ void k_hist(const int* __restrict__ dst, int* __restrict__ cnt){
  int i = blockIdx.x * 256 + threadIdx.x;
  if (i >= ETOT) return;
  int d = (i < EE) ? dst[i] : (i - EE);
  atomicAdd(&cnt[d], 1);
}

__global__ void k_scan1(const int* __restrict__ cnt, int* __restrict__ part){
  __shared__ int sm[256];
  int b = blockIdx.x, t = threadIdx.x;
  int base = b * 1024 + t * 4;
  int s = 0;
  #pragma unroll
  for (int j = 0; j < 4; j++) if (base + j < NN) s += cnt[base + j];
  sm[t] = s; __syncthreads();
  for (int off = 128; off; off >>= 1){
    if (t < off) sm[t] += sm[t + off];
    __syncthreads();
  }
  if (t == 0) part[b] = sm[0];
}

__global__ void k_scan2(const int* __restrict__ part, int* __restrict__ part2){
  if (threadIdx.x == 0 && blockIdx.x == 0){
    int run = 0;
    for (int i = 0; i < NSCAN; i++){ part2[i] = run; run += part[i]; }
  }
}

__global__ void k_scan3(const int* __restrict__ cnt, const int* __restrict__ part2,
                        int* __restrict__ rowptr){
  __shared__ int sm[256];
  int b = blockIdx.x, t = threadIdx.x;
  int base = b * 1024 + t * 4;
  int v[4]; int s = 0;
  #pragma unroll
  for (int j = 0; j < 4; j++){ v[j] = (base + j < NN) ? cnt[base + j] : 0; s += v[j]; }
  sm[t] = s; __syncthreads();
  for (int off = 1; off < 256; off <<= 1){
    int x = (t >= off) ? sm[t - off] : 0;
    __syncthreads();
    sm[t] += x;
    __syncthreads();
  }
  int run = part2[b] + sm[t] - s;
  #pragma unroll
  for (int j = 0; j < 4; j++){
    if (base + j < NN){ rowptr[base + j] = run; run += v[j]; }
  }
  if (b == 0 && t == 0) rowptr[NN] = ETOT;
}

__global__ void k_scatter(const int* __restrict__ src, const int* __restrict__ dst,
                          const int* __restrict__ rowptr, int* __restrict__ fill,
                          int* __restrict__ csr){
  int i = blockIdx.x * 256 + threadIdx.x;
  if (i >= ETOT) return;
  int s, d;
  if (i < EE){ s = src[i]; d = dst[i]; } else { s = d = i - EE; }
  int pos = rowptr[d] + atomicAdd(&fill[d], 1);
  csr[pos] = s;
}

// ---------------- weight conversion: fp32 [.,K,N] -> bf16 hi/lo [.,K/8,N,8] ----
__global__ void k_convB(const float* __restrict__ B, unsigned short* __restrict__ bh,
                        unsigned short* __restrict__ bl, int K, int N, int total){
  int i = blockIdx.x * 256 + threadIdx.x;
  if (i >= total) return;
  int per = K * N;
  int h = i / per, rem = i - h * per;
  int k = rem / N, n = rem - k * N;
  float x = B[i];
  unsigned u = __float_as_uint(x);
  unsigned short hb = (unsigned short)(u >> 16);
  unsigned short lb = f2bf_rne(x - __uint_as_float(u & 0xffff0000u));
  size_t o = (size_t)h * per + ((size_t)(k >> 3) * N + n) * 8 + (k & 7);
  bh[o] = hb; bl[o] = lb;
}

// ---------------- split-bf16 MFMA GEMM, fused att-dots + slice-major f16 out ----
// tabO[(col>>5)*NN*32 + row*32 + (col&31)] (f16); ssrc/sdst[row*SST + h].
template<int BN, int SST, bool AHALF>
__global__ __launch_bounds__(256) void gemm_fused(const void* __restrict__ Ax,
                                                  const unsigned short* __restrict__ Bh,
                                                  const unsigned short* __restrict__ Bl,
                                                  const float* __restrict__ attS,
                                                  const float* __restrict__ attD,
                                                  unsigned short* __restrict__ tabO,
                                                  float* __restrict__ ssrc,
                                                  float* __restrict__ sdst,
                                                  int M, int K){
  const int t = threadIdx.x;
  const int wv = t >> 6, lane = t & 63;
  const int m0 = blockIdx.x * 128;
  const int h = blockIdx.y;
  const size_t aoff = (size_t)h * M * K;
  Bh += (size_t)h * (K >> 3) * BN * 8;
  Bl += (size_t)h * (K >> 3) * BN * 8;

  __shared__ v8bf sAh[4][128];
  __shared__ v8bf sAl[4][128];
  __shared__ v8bf sBh[4][BN];
  __shared__ v8bf sBl[4][BN];

  f32x4 acc[2][BN / 16];
  #pragma unroll
  for (int i = 0; i < 2; i++)
    #pragma unroll
    for (int j = 0; j < BN / 16; j++){
      f32x4 z = {0.f, 0.f, 0.f, 0.f};
      acc[i][j] = z;
    }

  const int mRow = t & 127;
  const int kh = (t >> 7) * 16;
  const bool valid = (m0 + mRow) < M;
  const int q = lane >> 4, lm = lane & 15;

  for (int k0 = 0; k0 < K; k0 += 32){
    // ---- stage A: load 16 elems, split hi(trunc)/lo(rne) ----
    float xv[16];
    if (AHALF){
      const unsigned short* ap = (const unsigned short*)Ax + aoff + (size_t)(m0 + mRow) * K + k0 + kh;
      uint4 ua = make_uint4(0,0,0,0), ub = make_uint4(0,0,0,0);
      if (valid){ ua = *(const uint4*)ap; ub = *(const uint4*)(ap + 8); }
      xv[0]=f16_lo(ua.x); xv[1]=f16_hi(ua.x); xv[2]=f16_lo(ua.y); xv[3]=f16_hi(ua.y);
      xv[4]=f16_lo(ua.z); xv[5]=f16_hi(ua.z); xv[6]=f16_lo(ua.w); xv[7]=f16_hi(ua.w);
      xv[8]=f16_lo(ub.x); xv[9]=f16_hi(ub.x); xv[10]=f16_lo(ub.y); xv[11]=f16_hi(ub.y);
      xv[12]=f16_lo(ub.z); xv[13]=f16_hi(ub.z); xv[14]=f16_lo(ub.w); xv[15]=f16_hi(ub.w);
    } else {
      const float* ap = (const float*)Ax + aoff + (size_t)(m0 + mRow) * K + k0 + kh;
      float4 v0, v1, v2, v3;
      if (valid){
        v0 = *(const float4*)(ap);
        v1 = *(const float4*)(ap + 4);
        v2 = *(const float4*)(ap + 8);
        v3 = *(const float4*)(ap + 12);
      } else {
        v0 = v1 = v2 = v3 = make_float4(0.f, 0.f, 0.f, 0.f);
      }
      xv[0]=v0.x; xv[1]=v0.y; xv[2]=v0.z; xv[3]=v0.w;
      xv[4]=v1.x; xv[5]=v1.y; xv[6]=v1.z; xv[7]=v1.w;
      xv[8]=v2.x; xv[9]=v2.y; xv[10]=v2.z; xv[11]=v2.w;
      xv[12]=v3.x; xv[13]=v3.y; xv[14]=v3.z; xv[15]=v3.w;
    }
    #pragma unroll
    for (int g = 0; g < 2; g++){
      union { v8bf v; unsigned short u[8]; } H, L;
      #pragma unroll
      for (int i = 0; i < 8; i++){
        float x = xv[g * 8 + i];
        unsigned ux = __float_as_uint(x);
        H.u[i] = (unsigned short)(ux >> 16);
        L.u[i] = f2bf_rne(x - __uint_as_float(ux & 0xffff0000u));
      }
      int k8 = (kh >> 3) + g;
      sAh[k8][mRow] = H.v;
      sAl[k8][mRow] = L.v;
    }
    // ---- stage B ----
    {
      const v8bf* gh = (const v8bf*)Bh + (size_t)(k0 >> 3) * BN;
      const v8bf* gl = (const v8bf*)Bl + (size_t)(k0 >> 3) * BN;
      v8bf* dh = &sBh[0][0];
      v8bf* dl = &sBl[0][0];
      #pragma unroll
      for (int i = t; i < 4 * BN; i += 256){ dh[i] = gh[i]; dl[i] = gl[i]; }
    }
    __syncthreads();
    v8bf ah[2], al[2];
    #pragma unroll
    for (int rt = 0; rt < 2; rt++){
      int m = wv * 32 + rt * 16 + lm;
      ah[rt] = sAh[q][m];
      al[rt] = sAl[q][m];
    }
    #pragma unroll
    for (int ct = 0; ct < BN / 16; ct++){
      v8bf bh = sBh[q][ct * 16 + lm];
      v8bf bl = sBl[q][ct * 16 + lm];
      #pragma unroll
      for (int rt = 0; rt < 2; rt++){
        acc[rt][ct] = __builtin_amdgcn_mfma_f32_16x16x32_bf16(ah[rt], bh, acc[rt][ct], 0, 0, 0);
        acc[rt][ct] = __builtin_amdgcn_mfma_f32_16x16x32_bf16(ah[rt], bl, acc[rt][ct], 0, 0, 0);
        acc[rt][ct] = __builtin_amdgcn_mfma_f32_16x16x32_bf16(al[rt], bh, acc[rt][ct], 0, 0, 0);
      }
    }
    __syncthreads();
  }

  // ---- epilogue 1: fused attention dots (full head in this block) ----
  float asv[BN / 16], adv[BN / 16];
  #pragma unroll
  for (int ct = 0; ct < BN / 16; ct++){
    asv[ct] = attS[h * BN + ct * 16 + lm];
    adv[ct] = attD[h * BN + ct * 16 + lm];
  }
  #pragma unroll
  for (int rt = 0; rt < 2; rt++){
    #pragma unroll
    for (int reg = 0; reg < 4; reg++){
      int r = m0 + wv * 32 + rt * 16 + q * 4 + reg;
      float ds = 0.f, dd = 0.f;
      #pragma unroll
      for (int ct = 0; ct < BN / 16; ct++){
        float v = acc[rt][ct][reg];
        ds += v * asv[ct];
        dd += v * adv[ct];
      }
      #pragma unroll
      for (int off = 1; off < 16; off <<= 1){
        ds += __shfl_xor(ds, off, 64);
        dd += __shfl_xor(dd, off, 64);
      }
      if (lm == 0 && r < M){
        ssrc[(size_t)r * SST + h] = ds;
        sdst[(size_t)r * SST + h] = dd;
      }
    }
  }
  // ---- epilogue 2: slice-major f16 table ----
  #pragma unroll
  for (int rt = 0; rt < 2; rt++){
    #pragma unroll
    for (int reg = 0; reg < 4; reg++){
      int r = m0 + wv * 32 + rt * 16 + q * 4 + reg;
      if (r < M){
        #pragma unroll
        for (int ct = 0; ct < BN / 16; ct++){
          int col = h * BN + ct * 16 + lm;
          union { _Float16 f; unsigned short s; } cv;
          cv.f = (_Float16)acc[rt][ct][reg];
          tabO[((size_t)(col >> 5) * NN + r) * 32 + (col & 31)] = cv.s;
        }
      }
    }
  }
}

// ---------------- layer-1 per-head packed softmax meta (src u16 | w f16) ----
__global__ __launch_bounds__(256) void k_meta4(const int* __restrict__ rowptr,
                                               const int* __restrict__ csr,
                                               const float* __restrict__ ssrc,
                                               const float* __restrict__ sdst,
                                               unsigned* __restrict__ meta){
  int n = (blockIdx.x * 256 + threadIdx.x) >> 6;
  int lane = threadIdx.x & 63;
  if (n >= NN) return;
  int start = rowptr[n], end = rowptr[n + 1];
  float4 sd = ((const float4*)sdst)[n];

  float s0 = 0.f, s1 = 0.f, s2 = 0.f, s3 = 0.f;
  for (int e = start + lane; e < end; e += 64){
    float4 sv = ((const float4*)ssrc)[csr[e]];
    s0 += __expf(lrelu(sv.x + sd.x));
    s1 += __expf(lrelu(sv.y + sd.y));
    s2 += __expf(lrelu(sv.z + sd.z));
    s3 += __expf(lrelu(sv.w + sd.w));
  }
  #pragma unroll
  for (int off = 32; off; off >>= 1){
    s0 += __shfl_xor(s0, off, 64);
    s1 += __shfl_xor(s1, off, 64);
    s2 += __shfl_xor(s2, off, 64);
    s3 += __shfl_xor(s3, off, 64);
  }
  float i0 = 1.f / s0, i1 = 1.f / s1, i2 = 1.f / s2, i3 = 1.f / s3;

  for (int e = start + lane; e < end; e += 64){
    int src = csr[e];
    float4 sv = ((const float4*)ssrc)[src];
    meta[e]            = pack_sw(src, __expf(lrelu(sv.x + sd.x)) * i0);
    meta[ETOT + e]     = pack_sw(src, __expf(lrelu(sv.y + sd.y)) * i1);
    meta[2 * ETOT + e] = pack_sw(src, __expf(lrelu(sv.z + sd.z)) * i2);
    meta[3 * ETOT + e] = pack_sw(src, __expf(lrelu(sv.w + sd.w)) * i3);
  }
}

// ---------------- layer-1 gather: S=16 XCD-pinned slices, wave-per-node,
// 4 edges per j-step (quarter-wave per edge), 2 loads in flight ----
__global__ __launch_bounds__(256) void k_gat1(const int* __restrict__ rowptr,
                                              const unsigned* __restrict__ meta,
                                              const unsigned* __restrict__ tab,
                                              const float* __restrict__ bias,
                                              unsigned* __restrict__ x1){
  int b = blockIdx.x;
  int p = b / 12504;
  int r = b - p * 12504;
  int xcd = r & 7, blk = r >> 3;           // blk 0..1562
  int slice = p * 8 + xcd;                 // 0..15
  int head = slice >> 2;
  int wv = threadIdx.x >> 6, lane = threadIdx.x & 63;
  int q = lane >> 4, l = lane & 15;
  const unsigned* mh = meta + (size_t)head * ETOT;
  const unsigned* tbl = tab + (size_t)slice * NN * 16 + l;
  float b0 = bias[slice * 32 + l * 2];
  float b1 = bias[slice * 32 + l * 2 + 1];
  int nbase = (blk * 4 + wv) * 8;
  for (int nn = 0; nn < 8; nn++){
    int n = nbase + nn;
    if (n >= NN) break;
    int start = rowptr[n], end = rowptr[n + 1];
    float a0 = 0.f, a1 = 0.f;
    for (int cb = start; cb < end; cb += 64){
      int e = cb + lane;
      unsigned m = 0;
      if (e < end) m = __builtin_nontemporal_load(mh + e);
      int cnt = min(64, end - cb);
      for (int j = 0; j < cnt; j += 8){
        unsigned s0 = bcast_u(m, j),     s1 = bcast_u(m, j + 1);
        unsigned s2 = bcast_u(m, j + 2), s3 = bcast_u(m, j + 3);
        unsigned s4 = bcast_u(m, j + 4), s5 = bcast_u(m, j + 5);
        unsigned s6 = bcast_u(m, j + 6), s7 = bcast_u(m, j + 7);
        unsigned A = (q == 0) ? s0 : (q == 1) ? s1 : (q == 2) ? s2 : s3;
        unsigned B = (q == 0) ? s4 : (q == 1) ? s5 : (q == 2) ? s6 : s7;
        unsigned ta = tbl[(A & 0xffffu) * 16];
        unsigned tb = tbl[(B & 0xffffu) * 16];
        float wa = f16_hi(A), wb = f16_hi(B);
        a0 += wa * f16_lo(ta); a1 += wa * f16_hi(ta);
        a0 += wb * f16_lo(tb); a1 += wb * f16_hi(tb);
      }
    }
    // cross-quarter reduce (quarters hold disjoint edge subsets)
    a0 += __shfl_xor(a0, 16, 64); a0 += __shfl_xor(a0, 32, 64);
    a1 += __shfl_xor(a1, 16, 64); a1 += __shfl_xor(a1, 32, 64);
    if (q == 0){
      unsigned pk = pack_f16x2(lrelu(a0 + b0), lrelu(a1 + b1));
      __builtin_nontemporal_store(pk, x1 + (size_t)n * 256 + slice * 16 + l);
    }
  }
}

// ---------------- layer-2 packed meta ----------------
__global__ __launch_bounds__(256) void k_meta1(const int* __restrict__ rowptr,
                                               const int* __restrict__ csr,
                                               const float* __restrict__ ssrc,
                                               const float* __restrict__ sdst,
                                               unsigned* __restrict__ meta){
  int n = (blockIdx.x * 256 + threadIdx.x) >> 6;
  int lane = threadIdx.x & 63;
  if (n >= NN) return;
  int start = rowptr[n], end = rowptr[n + 1];
  float sdn = sdst[n];

  float sloc = 0.f;
  for (int e = start + lane; e < end; e += 64)
    sloc += __expf(lrelu(ssrc[csr[e]] + sdn));
  #pragma unroll
  for (int off = 32; off; off >>= 1) sloc += __shfl_xor(sloc, off, 64);
  float inv = 1.f / sloc;

  for (int e = start + lane; e < end; e += 64){
    int src = csr[e];
    meta[e] = pack_sw(src, __expf(lrelu(ssrc[src] + sdn)) * inv);
  }
}

// ---------------- layer-2 gather: S=2 slices, 4 XCDs/slice ----------------
__global__ __launch_bounds__(256) void k_gat2(const int* __restrict__ rowptr,
                                              const unsigned* __restrict__ meta,
                                              const unsigned* __restrict__ tab,
                                              const float* __restrict__ bias,
                                              float* __restrict__ outp){
  int b = blockIdx.x;
  int xcd = b & 7, g = b >> 3;             // g 0..390
  int slice = xcd & 1;
  int quad = xcd >> 1;                     // 0..3
  int c = g * 4 + quad;                    // 0..1563
  int wv = threadIdx.x >> 6, lane = threadIdx.x & 63;
  int q = lane >> 4, l = lane & 15;
  const unsigned* tbl = tab + (size_t)slice * NN * 16 + l;
  float b0 = bias[slice * 32 + l * 2];
  float b1 = bias[slice * 32 + l * 2 + 1];
  int nbase = (c * 4 + wv) * 8;
  for (int nn = 0; nn < 8; nn++){
    int n = nbase + nn;
    if (n >= NN) break;
    int start = rowptr[n], end = rowptr[n + 1];
    float a0 = 0.f, a1 = 0.f;
    for (int cb = start; cb < end; cb += 64){
      int e = cb + lane;
      unsigned m = 0;
      if (e < end) m = __builtin_nontemporal_load(meta + e);
      int cnt = min(64, end - cb);
      for (int j = 0; j < cnt; j += 8){
        unsigned s0 = bcast_u(m, j),     s1 = bcast_u(m, j + 1);
        unsigned s2 = bcast_u(m, j + 2), s3 = bcast_u(m, j + 3);
        unsigned s4 = bcast_u(m, j + 4), s5 = bcast_u(m, j + 5);
        unsigned s6 = bcast_u(m, j + 6), s7 = bcast_u(m, j + 7);
        unsigned A = (q == 0) ? s0 : (q == 1) ? s1 : (q == 2) ? s2 : s3;
        unsigned B = (q == 0) ? s4 : (q == 1) ? s5 : (q == 2) ? s6 : s7;
        unsigned ta = tbl[(A & 0xffffu) * 16];
        unsigned tb = tbl[(B & 0xffffu) * 16];
        float wa = f16_hi(A), wb = f16_hi(B);
        a0 += wa * f16_lo(ta); a1 += wa * f16_hi(ta);
        a0 += wb * f16_lo(tb); a1 += wb * f16_hi(tb);
      }
    }
    a0 += __shfl_xor(a0, 16, 64); a0 += __shfl_xor(a0, 32, 64);
    a1 += __shfl_xor(a1, 16, 64); a1 += __shfl_xor(a1, 32, 64);
    if (q == 0){
      f32x2 o;
      o.x = tanhf(lrelu(a0 + b0));
      o.y = tanhf(lrelu(a1 + b1));
      __builtin_nontemporal_store(o, (f32x2*)(outp + (size_t)n * 64 + slice * 32 + l * 2));
    }
  }
}

extern "C" void kernel_launch(void* const* d_in, const int* in_sizes, int n_in,
                              void* d_out, int out_size, void* d_ws, size_t ws_size,
                              hipStream_t stream){
  const float* type_emb  = (const float*)d_in[0];
  const int*   edge      = (const int*)d_in[1];
  const float* W         = (const float*)d_in[2];
  const float* att_src   = (const float*)d_in[3];
  const float* att_dst   = (const float*)d_in[4];
  const float* bias      = (const float*)d_in[5];
  const float* W_out     = (const float*)d_in[6];
  const float* att_src_o = (const float*)d_in[7];
  const float* att_dst_o = (const float*)d_in[8];
  const float* bias_o    = (const float*)d_in[9];
  float* out = (float*)d_out;
  (void)in_sizes; (void)n_in; (void)out_size; (void)ws_size;

  char* ws = (char*)d_ws;
  size_t off = 0;
  auto alloc = [&](size_t bytes) -> void* {
    void* p = ws + off;
    off = (off + bytes + 255) & ~(size_t)255;
    return p;
  };
  unsigned short* tab1 = (unsigned short*)alloc((size_t)NN * 512 * 2);  // [16][N][32] f16
  unsigned*       x1   = (unsigned*)alloc((size_t)NN * 512 * 2);        // [N][512] f16 (uint-packed)
  unsigned short* tab2 = (unsigned short*)alloc((size_t)NN * 64 * 2);   // [2][N][32] f16
  unsigned* meta4 = (unsigned*)alloc((size_t)4 * ETOT * 4);             // [4][E] (src|w)
  unsigned* meta2 = (unsigned*)alloc((size_t)ETOT * 4);                 // [E]
  float* ssrc1 = (float*)alloc((size_t)NN * 4 * 4);
  float* sdst1 = (float*)alloc((size_t)NN * 4 * 4);
  float* ssrc2 = (float*)alloc((size_t)NN * 4);
  float* sdst2 = (float*)alloc((size_t)NN * 4);
  int* cnt    = (int*)alloc((size_t)NN * 4);
  int* rowptr = (int*)alloc((size_t)(NN + 1) * 4);
  int* fill   = (int*)alloc((size_t)NN * 4);
  int* csr    = (int*)alloc((size_t)ETOT * 4);
  int* p1     = (int*)alloc((size_t)NSCAN * 4 + 256);
  int* p2     = (int*)alloc((size_t)NSCAN * 4 + 256);
  unsigned short* Bh1 = (unsigned short*)alloc((size_t)4 * 128 * 128 * 2);
  unsigned short* Bl1 = (unsigned short*)alloc((size_t)4 * 128 * 128 * 2);
  unsigned short* Bh2 = (unsigned short*)alloc((size_t)512 * 64 * 2);
  unsigned short* Bl2 = (unsigned short*)alloc((size_t)512 * 64 * 2);

  // ---- CSR build (dst-sorted) ----
  hipMemsetAsync(cnt, 0, (size_t)NN * 4, stream);
  hipMemsetAsync(fill, 0, (size_t)NN * 4, stream);
  k_hist<<<(ETOT + 255) / 256, 256, 0, stream>>>(edge + EE, cnt);
  k_scan1<<<NSCAN, 256, 0, stream>>>(cnt, p1);
  k_scan2<<<1, 64, 0, stream>>>(p1, p2);
  k_scan3<<<NSCAN, 256, 0, stream>>>(cnt, p2, rowptr);
  k_scatter<<<(ETOT + 255) / 256, 256, 0, stream>>>(edge, edge + EE, rowptr, fill, csr);

  // ---- weight conversion ----
  k_convB<<<(4 * 128 * 128 + 255) / 256, 256, 0, stream>>>(W, Bh1, Bl1, 128, 128, 4 * 128 * 128);
  k_convB<<<(512 * 64 + 255) / 256, 256, 0, stream>>>(W_out, Bh2, Bl2, 512, 64, 512 * 64);

  // ---- layer 1 ----
  gemm_fused<128, 4, false><<<dim3(391, 4), 256, 0, stream>>>(
      type_emb, Bh1, Bl1, att_src, att_dst, tab1, ssrc1, sdst1, NN, 128);
  k_meta4<<<12500, 256, 0, stream>>>(rowptr, csr, ssrc1, sdst1, meta4);
  k_gat1<<<25008, 256, 0, stream>>>(rowptr, meta4, (const unsigned*)tab1, bias, x1);

  // ---- layer 2 ----
  gemm_fused<64, 1, true><<<dim3(391, 1), 256, 0, stream>>>(
      x1, Bh2, Bl2, att_src_o, att_dst_o, tab2, ssrc2, sdst2, NN, 512);
  k_meta1<<<12500, 256, 0, stream>>>(rowptr, csr, ssrc2, sdst2, meta2);
  k_gat2<<<3128, 256, 0, stream>>>(rowptr, meta2, (const unsigned*)tab2, bias_o, out);
}